// Round 15
// baseline (532.487 us; speedup 1.0000x reference)
//
#include <hip/hip_runtime.h>
#include <cstdint>
#include <cstddef>

// C[4096,4096] = sum_r input[r] @ weight[r]^T  == GEMM M=N=4096, K=8192, fp32 out.
// Phase 1: fp32 -> bf16 cast, R0 version (~80us real; dur_us carries ~170us of
//          fixed non-kernel overhead — cast is near its roofline).
// Phase 2: R19: 128x128-tile, 2-blocks/CU, double-buffered counted-vmcnt GEMM.
//          R16 (256², 218us, MfmaUtil 56%) is a SINGLE block/CU: at every
//          phase barrier the whole CU idles together (no second barrier
//          domain). This kernel = R0's proven 128² kernel (same wave geometry,
//          staging map, swizzle, reads, epilogue — passed repeatedly) +
//          the two levers validated this session: LDS double-buffer with
//          counted VM8 (FIFO ledger: 8 loads of t+1 outstanding; stage t+2
//          adds 8; VM8 retires exactly t+1's) and 1-tile prefetch lead.
//          64KB LDS -> 2 blocks/CU -> cross-block pipe overlap (m114/m97
//          mechanism our 256² design removed).
//          (R13/R14 32x32x16 port: failed absmax twice w/ consistent math ->
//          retired per pre-commitment. R15 even-read: falsified. R8/R5/R7:
//          reverted. R12's sched_barrier kept implicitly via simple order.)

#define M_DIM 4096
#define N_DIM 4096
#define K_DIM 8192
#define K_LOCAL 1024
#define RANKS 8
#define NT 128  // K-tiles: RANKS * (K_LOCAL/64)

typedef __bf16 bf16x8 __attribute__((ext_vector_type(8)));
typedef float f32x4 __attribute__((ext_vector_type(4)));

__device__ __forceinline__ unsigned short f2bf(float f) {
    unsigned int u = __float_as_uint(f);
    unsigned int r = (u + 0x7fffu + ((u >> 16) & 1u)) >> 16;
    return (unsigned short)r;
}

// ---------- Phase 1: linear fp32 -> bf16 cast (R0 version) ----------
__global__ __launch_bounds__(256) void convert_cast(
    const float* __restrict__ srcA, unsigned short* __restrict__ dstA,
    const float* __restrict__ srcB, unsigned short* __restrict__ dstB,
    int blocks_per_tensor) {
    const float* src = srcA;
    unsigned short* dst = dstA;
    int b = blockIdx.x;
    if (b >= blocks_per_tensor) { b -= blocks_per_tensor; src = srcB; dst = dstB; }
    size_t base = (size_t)b * 4096 + threadIdx.x * 4;
#pragma unroll
    for (int i = 0; i < 4; ++i) {
        size_t e = base + i * 1024;
        f32x4 v = __builtin_nontemporal_load((const f32x4*)(src + e));
        ushort4 o;
        o.x = f2bf(v.x); o.y = f2bf(v.y); o.z = f2bf(v.z); o.w = f2bf(v.w);
        *(ushort4*)(dst + e) = o;
    }
}

// ---------- Phase 2: 128^2 dbuf counted-vmcnt bf16 MFMA GEMM ----------
__device__ __forceinline__ void async_copy16(const unsigned short* g, unsigned short* l) {
    __builtin_amdgcn_global_load_lds(
        (const __attribute__((address_space(1))) void*)g,
        (__attribute__((address_space(3))) void*)l,
        16, 0, 0);
}

#define VM8() asm volatile("s_waitcnt vmcnt(8)" ::: "memory")
#define VM0() asm volatile("s_waitcnt vmcnt(0)" ::: "memory")
#define BAR() __builtin_amdgcn_s_barrier()

__global__ __launch_bounds__(256, 2) void gemm_bf16(
    const unsigned short* __restrict__ A,  // [R, M, K_LOCAL] bf16
    const unsigned short* __restrict__ B,  // [R, N, K_LOCAL] bf16
    float* __restrict__ C) {               // [M, N] fp32
    // [buf][128 rows][64 k] flattened; 16B chunk c of row r stored at
    // chunk c ^ (r & 7)  (R0-proven, 0 conflicts). 64KB total -> 2 blocks/CU.
    __shared__ __align__(16) unsigned short As[2][128 * 64];
    __shared__ __align__(16) unsigned short Bs[2][128 * 64];

    const int tid = threadIdx.x;   // 0..255
    const int lane = tid & 63;
    const int wave = tid >> 6;     // 0..3
    const int wm = (wave >> 1) * 64;
    const int wn = (wave & 1) * 64;
    const int l15 = lane & 15;
    const int l4 = lane >> 4;

    // XCD-aware 2x2 supertile swizzle (R0-proven for 1024 blocks).
    const int bid = blockIdx.x;            // 0..1023
    const int xcd = bid & 7;
    const int q = bid >> 3;                // 0..127
    const int st = (q >> 2) * 8 + xcd;     // supertile 0..255 (16x16 grid)
    const int pos = q & 3;
    const int bm0 = ((st >> 4) * 2 + (pos >> 1)) * 128;
    const int bn0 = ((st & 15) * 2 + (pos & 1)) * 128;

    // Staging: 1024 chunks of 16B per tensor per tile; cc = p*256 + tid:
    // row = cc>>3, stored chunk cpos = cc&7 holds global chunk cpos^(row&7).
    const unsigned short* ga[4];
    const unsigned short* gb[4];
    int lo[4];
#pragma unroll
    for (int p = 0; p < 4; ++p) {
        int cc = p * 256 + tid;
        int row = cc >> 3;
        int g = (cc & 7) ^ (row & 7);
        ga[p] = A + (size_t)(bm0 + row) * K_LOCAL + g * 8;
        gb[p] = B + (size_t)(bn0 + row) * K_LOCAL + g * 8;
        lo[p] = cc * 8;  // ushort units
    }

    auto STAGE = [&](int t, int buf) {
        const size_t off = (size_t)(t >> 4) * ((size_t)M_DIM * K_LOCAL)
                         + (size_t)((t & 15) << 6);
#pragma unroll
        for (int p = 0; p < 4; ++p)
            async_copy16(ga[p] + off, &As[buf][lo[p]]);
#pragma unroll
        for (int p = 0; p < 4; ++p)
            async_copy16(gb[p] + off, &Bs[buf][lo[p]]);
    };

    const int swz0 = ((l4 + 0) ^ (l15 & 7)) * 8;  // ks = 0
    const int swz1 = ((l4 + 4) ^ (l15 & 7)) * 8;  // ks = 1
    const int a_row = (wm + l15) * 64;
    const int b_row = (wn + l15) * 64;

    f32x4 acc[4][4] = {};

    // Prologue: tile0 -> buf0 (8 loads), tile1 -> buf1 (8 loads).
    // VM8 retires exactly tile0's 8 (FIFO); BAR publishes.
    STAGE(0, 0);
    STAGE(1, 1);
    VM8(); BAR();

    for (int t = 0; t < NT; ++t) {
        const int cur = t & 1;
        const unsigned short* as = &As[cur][0];
        const unsigned short* bs = &Bs[cur][0];
#pragma unroll
        for (int ks = 0; ks < 2; ++ks) {
            const int swz = ks ? swz1 : swz0;
            bf16x8 af[4], bfr[4];
#pragma unroll
            for (int i = 0; i < 4; ++i)
                af[i] = *(const bf16x8*)&as[a_row + i * 1024 + swz];
#pragma unroll
            for (int j = 0; j < 4; ++j)
                bfr[j] = *(const bf16x8*)&bs[b_row + j * 1024 + swz];
            __builtin_amdgcn_s_setprio(1);
#pragma unroll
            for (int i = 0; i < 4; ++i)
#pragma unroll
                for (int j = 0; j < 4; ++j)
                    acc[i][j] = __builtin_amdgcn_mfma_f32_16x16x32_bf16(
                        af[i], bfr[j], acc[i][j], 0, 0, 0);
            __builtin_amdgcn_s_setprio(0);
        }
        BAR();  // all waves done reading buf[cur] (reads drained by MFMA deps)
        if (t + 2 < NT) {
            STAGE(t + 2, cur);   // refill freed buffer
            VM8();               // retire tile t+1's 8 loads (FIFO)
        } else {
            VM0();               // tail: drain remaining (tile t+1 or none)
        }
        BAR();  // publish tile t+1 landed
    }

    // Epilogue: C/D layout col = lane&15, row = (lane>>4)*4 + reg (R0-proven).
#pragma unroll
    for (int i = 0; i < 4; ++i) {
        int row0 = bm0 + wm + i * 16 + l4 * 4;
#pragma unroll
        for (int j = 0; j < 4; ++j) {
            int col = bn0 + wn + j * 16 + l15;
#pragma unroll
            for (int r = 0; r < 4; ++r)
                C[(size_t)(row0 + r) * N_DIM + col] = acc[i][j][r];
        }
    }
}

// ---------- Fallback (ws too small): naive fp32 tiled GEMM ----------
__global__ void gemm_naive(const float* __restrict__ A, const float* __restrict__ B,
                           float* __restrict__ C) {
    __shared__ float As[16][17];
    __shared__ float Bs[16][17];
    int tx = threadIdx.x, ty = threadIdx.y;
    int m = blockIdx.y * 16 + ty;
    int n0 = blockIdx.x * 16;
    float accv = 0.f;
    for (int kt = 0; kt < K_DIM; kt += 16) {
        int r = kt >> 10;
        int k = (kt & 1023) + tx;
        As[ty][tx] = A[((size_t)r * M_DIM + m) * K_LOCAL + k];
        Bs[ty][tx] = B[((size_t)r * N_DIM + (n0 + ty)) * K_LOCAL + k];
        __syncthreads();
#pragma unroll
        for (int kk = 0; kk < 16; ++kk) accv += As[ty][kk] * Bs[tx][kk];
        __syncthreads();
    }
    C[(size_t)m * N_DIM + n0 + tx] = accv;
}

extern "C" void kernel_launch(void* const* d_in, const int* in_sizes, int n_in,
                              void* d_out, int out_size, void* d_ws, size_t ws_size,
                              hipStream_t stream) {
    const float* inp = (const float*)d_in[0];
    const float* wgt = (const float*)d_in[1];
    float* out = (float*)d_out;

    const size_t elems = (size_t)M_DIM * K_DIM;              // 33,554,432 per tensor
    const size_t need = 2 * elems * sizeof(unsigned short);  // 128 MiB

    if (ws_size >= need) {
        unsigned short* Abf = (unsigned short*)d_ws;
        unsigned short* Bbf = Abf + elems;
        const int bpt = (int)(elems / 4096);      // 8192 blocks per tensor
        convert_cast<<<bpt * 2, 256, 0, stream>>>(inp, Abf, wgt, Bbf, bpt);
        gemm_bf16<<<1024, 256, 0, stream>>>(Abf, Bbf, out);
    } else {
        dim3 grid(N_DIM / 16, M_DIM / 16);
        dim3 block(16, 16);
        gemm_naive<<<grid, block, 0, stream>>>(inp, wgt, out);
    }
}

// Round 16
// 503.347 us; speedup vs baseline: 1.0579x; 1.0579x over previous
//
#include <hip/hip_runtime.h>
#include <cstdint>
#include <cstddef>

// C[4096,4096] = sum_r input[r] @ weight[r]^T  == GEMM M=N=4096, K=8192, fp32 out.
// Phase 1: fp32 -> bf16 cast, R0 version (~78us real; dur_us carries ~170us of
//          fixed non-kernel overhead — cast is near its roofline).
// Phase 2: R20: even-read pipelined 8-phase GEMM. R16's reads were lumped
//          12/4/8/0 per phase -> P0's LDS-array time (1152cyc/CU) is 2.2x the
//          MFMA pipe (516cyc) while P3 idles the array. Fix: reads issue ONE
//          PHASE AHEAD of their consuming MFMA (zero self-dependency) ->
//          4/8/8/4 even: P0:b1R(t) P1:a1R(t) P2:aR(t1) P3:b0R(t1), mirrored.
//          Stage slots = R16 (deep leads). VM6 at P1/P3/P5/P7 ends; FIFO
//          ledger closed: invariant [B0,A0,B1](t+1)=6 entering P0; each VM6
//          retires exactly the 2 units the next 2 read-phases need; all
//          binding waits have 3-4-phase leads; all WAR pairs drained by an
//          earlier MFMA dep >=1 barrier before restage (NO lgkm drains —
//          R15's mistake). Cost: peak live frags 16->24 (+32 VGPR).
//          (R19 128²/2-blk: 287us, falsified. R13/R14 32x32: retired.)

#define M_DIM 4096
#define N_DIM 4096
#define K_DIM 8192
#define K_LOCAL 1024
#define RANKS 8
#define NT 128  // K-tiles: RANKS * (K_LOCAL/64)

typedef __bf16 bf16x8 __attribute__((ext_vector_type(8)));
typedef float f32x4 __attribute__((ext_vector_type(4)));

__device__ __forceinline__ unsigned short f2bf(float f) {
    unsigned int u = __float_as_uint(f);
    unsigned int r = (u + 0x7fffu + ((u >> 16) & 1u)) >> 16;
    return (unsigned short)r;
}

// ---------- Phase 1: linear fp32 -> bf16 cast (R0 version) ----------
__global__ __launch_bounds__(256) void convert_cast(
    const float* __restrict__ srcA, unsigned short* __restrict__ dstA,
    const float* __restrict__ srcB, unsigned short* __restrict__ dstB,
    int blocks_per_tensor) {
    const float* src = srcA;
    unsigned short* dst = dstA;
    int b = blockIdx.x;
    if (b >= blocks_per_tensor) { b -= blocks_per_tensor; src = srcB; dst = dstB; }
    size_t base = (size_t)b * 4096 + threadIdx.x * 4;
#pragma unroll
    for (int i = 0; i < 4; ++i) {
        size_t e = base + i * 1024;
        f32x4 v = __builtin_nontemporal_load((const f32x4*)(src + e));
        ushort4 o;
        o.x = f2bf(v.x); o.y = f2bf(v.y); o.z = f2bf(v.z); o.w = f2bf(v.w);
        *(ushort4*)(dst + e) = o;
    }
}

// ---------- Phase 2: 256^2 even-read pipelined 8-phase bf16 MFMA GEMM ----------
__device__ __forceinline__ void async_copy16(const unsigned short* g, unsigned short* l) {
    __builtin_amdgcn_global_load_lds(
        (const __attribute__((address_space(1))) void*)g,
        (__attribute__((address_space(3))) void*)l,
        16, 0, 0);
}

#define VM6()   asm volatile("s_waitcnt vmcnt(6)" ::: "memory")
#define VM0()   asm volatile("s_waitcnt vmcnt(0)" ::: "memory")
#define BAR()   __builtin_amdgcn_s_barrier()
#define SCHED0() __builtin_amdgcn_sched_barrier(0)

__global__ __launch_bounds__(512, 2) void gemm_bf16(
    const unsigned short* __restrict__ A,  // [R, M, K_LOCAL] bf16
    const unsigned short* __restrict__ B,  // [R, N, K_LOCAL] bf16
    float* __restrict__ C) {               // [M, N] fp32
    // Per-tensor-half regions: [buf][rowhalf][128 rows][64 k] (128B rows).
    // 16B chunk c of row r stored at chunk c ^ (r & 7) (0 conflicts, R3-R16).
    __shared__ __align__(16) unsigned short As[2][2][128][64];
    __shared__ __align__(16) unsigned short Bs[2][2][128][64];

    const int tid = threadIdx.x;   // 0..511
    const int lane = tid & 63;
    const int wave = tid >> 6;     // 0..7
    const int l15 = lane & 15;
    const int l4 = lane >> 4;      // 0..3
    const int wm2 = wave >> 2;     // 0..1 -> row block *128 (= A half read)
    const int wn4 = wave & 3;      // 0..3 -> col block *64

    // Bijective XCD swizzle: 256 blocks, each XCD owns a 4x8 tile sub-grid.
    const int bid = blockIdx.x;
    const int xcd = bid & 7;
    const int idx = bid >> 3;                       // 0..31
    const int trow = (xcd >> 1) * 4 + (idx >> 3);   // 0..15
    const int tcol = (xcd & 1) * 8 + (idx & 7);     // 0..15
    const int bm0 = trow * 256;
    const int bn0 = tcol * 256;

    // Stage unit = one tensor-half: 128 rows x 64 k x 2B = 16KB = 1024 chunks;
    // li = i*512 + tid: row = li>>3, cpos = li&7, global chunk g = cpos^(row&7).
    const unsigned short* gA[2];
    const unsigned short* gB[2];
    int lo[2];
#pragma unroll
    for (int i = 0; i < 2; ++i) {
        int li = i * 512 + tid;
        int row = li >> 3;
        int g = (li & 7) ^ (row & 7);
        gA[i] = A + (size_t)(bm0 + row) * K_LOCAL + g * 8;
        gB[i] = B + (size_t)(bn0 + row) * K_LOCAL + g * 8;
        lo[i] = li * 8;  // ushort units
    }

    auto stageA = [&](int t, int buf, int h) {
        const size_t off = (size_t)(t >> 4) * ((size_t)M_DIM * K_LOCAL)
                         + (size_t)((t & 15) << 6) + (size_t)h * (128 * K_LOCAL);
        unsigned short* l = &As[buf][h][0][0];
        async_copy16(gA[0] + off, l + lo[0]);
        async_copy16(gA[1] + off, l + lo[1]);
    };
    auto stageB = [&](int t, int buf, int h) {
        const size_t off = (size_t)(t >> 4) * ((size_t)M_DIM * K_LOCAL)
                         + (size_t)((t & 15) << 6) + (size_t)h * (128 * K_LOCAL);
        unsigned short* l = &Bs[buf][h][0][0];
        async_copy16(gB[0] + off, l + lo[0]);
        async_copy16(gB[1] + off, l + lo[1]);
    };

    // Fragment reads: k-chunk c = ks*4 + l4 stored at c ^ (row&7); frag rows
    // are <mult of 16> + l15, so row&7 == l15&7.
    const int swzk0 = ((l4 + 0) ^ (l15 & 7)) * 8;  // ks = 0
    const int swzk1 = ((l4 + 4) ^ (l15 & 7)) * 8;  // ks = 1
    const int hb = wn4 >> 1;                        // B half for this wave
    const int brow_base = (wn4 & 1) * 64 + l15;     // B row within half

    f32x4 acc[8][4] = {};
    bf16x8 aR[8], a1R[8], b0R[4], b1R[4];

    auto LDA = [&](bf16x8* dst, int buf, int mh) {
#pragma unroll
        for (int m = 0; m < 4; ++m) {
            const unsigned short* rp = &As[buf][wm2][mh * 64 + m * 16 + l15][0];
            dst[m * 2 + 0] = *(const bf16x8*)(rp + swzk0);
            dst[m * 2 + 1] = *(const bf16x8*)(rp + swzk1);
        }
    };
    auto LDB = [&](bf16x8* dst, int buf, int nh) {
#pragma unroll
        for (int n = 0; n < 2; ++n) {
            const unsigned short* rp = &Bs[buf][hb][brow_base + nh * 32 + n * 16][0];
            dst[n * 2 + 0] = *(const bf16x8*)(rp + swzk0);
            dst[n * 2 + 1] = *(const bf16x8*)(rp + swzk1);
        }
    };
    auto MFMA16 = [&](const bf16x8* a, const bf16x8* b, int mh, int nh) {
        __builtin_amdgcn_s_setprio(1);
#pragma unroll
        for (int m = 0; m < 4; ++m)
#pragma unroll
            for (int n = 0; n < 2; ++n)
#pragma unroll
                for (int ks = 0; ks < 2; ++ks)
                    acc[mh * 4 + m][nh * 2 + n] = __builtin_amdgcn_mfma_f32_16x16x32_bf16(
                        a[m * 2 + ks], b[n * 2 + ks], acc[mh * 4 + m][nh * 2 + n], 0, 0, 0);
        __builtin_amdgcn_s_setprio(0);
    };

    // Prologue: t0 all 4 units (8 loads), then B0/A0/B1 of t1 (6 loads).
    // VM6 retires exactly t0's 8; invariant queue [B0,A0,B1](t1)=6.
    // Pre-read aR(t0), b0R(t0) for P0's MFMA.
    stageA(0, 0, 0); stageA(0, 0, 1); stageB(0, 0, 0); stageB(0, 0, 1);
    stageB(1, 1, 0); stageA(1, 1, 0); stageB(1, 1, 1);
    VM6(); BAR();
    LDA(aR, 0, 0); LDB(b0R, 0, 0);

    // Per phase: {read-for-NEXT-phase; stage; SCHED0; MFMA (operands read in
    // an earlier phase); [VM6]; BAR}. Reads never feed their own phase.
    for (int i = 0; i < NT / 2; ++i) {
        const int t1 = 2 * i + 1;
        const int t2 = (2 * i + 2) & (NT - 1);
        const int t3 = (2 * i + 3) & (NT - 1);
        // P0: Q00(t) | read b1R(t)->P1 | stage A1(t1)
        LDB(b1R, 0, 1); stageA(t1, 1, 1);
        SCHED0(); MFMA16(aR, b0R, 0, 0); BAR();
        // P1: Q01(t) | read a1R(t)->P2 | stage B0(t2) | VM6: B0,A0(t1) land
        LDA(a1R, 0, 1); stageB(t2, 0, 0);
        SCHED0(); MFMA16(aR, b1R, 0, 1); VM6(); BAR();
        // P2: Q10(t) | read aR(t1)->P4 [A0(t1) landed P1] | stage A0(t2)
        LDA(aR, 1, 0); stageA(t2, 0, 0);
        SCHED0(); MFMA16(a1R, b0R, 1, 0); BAR();
        // P3: Q11(t) | read b0R(t1)->P4 [B0(t1) landed P1] | stage B1(t2)
        //     VM6: B1,A1(t1) land
        LDB(b0R, 1, 0); stageB(t2, 0, 1);
        SCHED0(); MFMA16(a1R, b1R, 1, 1); VM6(); BAR();
        // P4: Q00(t1) | read b1R(t1)->P5 [B1(t1) landed P3] | stage A1(t2)
        LDB(b1R, 1, 1); stageA(t2, 0, 1);
        SCHED0(); MFMA16(aR, b0R, 0, 0); BAR();
        // P5: Q01(t1) | read a1R(t1)->P6 [A1(t1) landed P3] | stage B0(t3)
        //     VM6: B0,A0(t2) land
        LDA(a1R, 1, 1); stageB(t3, 1, 0);
        SCHED0(); MFMA16(aR, b1R, 0, 1); VM6(); BAR();
        // P6: Q10(t1) | read aR(t2)->next P0 [A0(t2) landed P5] | stage A0(t3)
        LDA(aR, 0, 0); stageA(t3, 1, 0);
        SCHED0(); MFMA16(a1R, b0R, 1, 0); BAR();
        // P7: Q11(t1) | read b0R(t2)->next P0 [B0(t2) landed P5] | stage B1(t3)
        //     VM6: B1,A1(t2) land -> invariant restored
        LDB(b0R, 0, 0); stageB(t3, 1, 1);
        SCHED0(); MFMA16(a1R, b1R, 1, 1); VM6(); BAR();
    }
    VM0();  // drain outstanding DMA (incl. dead wrap-stages) before exit

    // Epilogue: C/D layout col = lane&15, row = (lane>>4)*4 + reg.
#pragma unroll
    for (int m = 0; m < 8; ++m) {
        int row0 = bm0 + wm2 * 128 + m * 16 + l4 * 4;
#pragma unroll
        for (int n = 0; n < 4; ++n) {
            int col = bn0 + wn4 * 64 + n * 16 + l15;
#pragma unroll
            for (int rr = 0; rr < 4; ++rr)
                C[(size_t)(row0 + rr) * N_DIM + col] = acc[m][n][rr];
        }
    }
}

// ---------- Fallback (ws too small): naive fp32 tiled GEMM ----------
__global__ void gemm_naive(const float* __restrict__ A, const float* __restrict__ B,
                           float* __restrict__ C) {
    __shared__ float As[16][17];
    __shared__ float Bs[16][17];
    int tx = threadIdx.x, ty = threadIdx.y;
    int m = blockIdx.y * 16 + ty;
    int n0 = blockIdx.x * 16;
    float accv = 0.f;
    for (int kt = 0; kt < K_DIM; kt += 16) {
        int r = kt >> 10;
        int k = (kt & 1023) + tx;
        As[ty][tx] = A[((size_t)r * M_DIM + m) * K_LOCAL + k];
        Bs[ty][tx] = B[((size_t)r * N_DIM + (n0 + ty)) * K_LOCAL + k];
        __syncthreads();
#pragma unroll
        for (int kk = 0; kk < 16; ++kk) accv += As[ty][kk] * Bs[tx][kk];
        __syncthreads();
    }
    C[(size_t)m * N_DIM + n0 + tx] = accv;
}

extern "C" void kernel_launch(void* const* d_in, const int* in_sizes, int n_in,
                              void* d_out, int out_size, void* d_ws, size_t ws_size,
                              hipStream_t stream) {
    const float* inp = (const float*)d_in[0];
    const float* wgt = (const float*)d_in[1];
    float* out = (float*)d_out;

    const size_t elems = (size_t)M_DIM * K_DIM;              // 33,554,432 per tensor
    const size_t need = 2 * elems * sizeof(unsigned short);  // 128 MiB

    if (ws_size >= need) {
        unsigned short* Abf = (unsigned short*)d_ws;
        unsigned short* Bbf = Abf + elems;
        const int bpt = (int)(elems / 4096);      // 8192 blocks per tensor
        convert_cast<<<bpt * 2, 256, 0, stream>>>(inp, Abf, wgt, Bbf, bpt);
        gemm_bf16<<<256, 512, 0, stream>>>(Abf, Bbf, out);
    } else {
        dim3 grid(N_DIM / 16, M_DIM / 16);
        dim3 block(16, 16);
        gemm_naive<<<grid, block, 0, stream>>>(inp, wgt, out);
    }
}

// Round 18
// 465.191 us; speedup vs baseline: 1.1447x; 1.0820x over previous
//
#include <hip/hip_runtime.h>
#include <cstdint>
#include <cstddef>

// C[4096,4096] = sum_r input[r] @ weight[r]^T  == GEMM M=N=4096, K=8192, fp32 out.
// Phase 1: R22 cast = R21 with the coverage bug fixed: R21 strode 4096 between
//          iters but only wrote 1024 elems/iter (3/4 of workspace unwritten,
//          absmax 0.19). Now: block owns 8192 elems, 8 iters x stride 1024;
//          nt loads (L3 protection), 1KB lane-contiguous per wave-instruction,
//          8-deep load batch before the store burst.
// Phase 2: gemm = R16 byte-identical (best: 218.5us, MfmaUtil 56%).
//          Session scaling law: runtime ∝ LDS-read traffic; decomposition at
//          the traffic minimum; all multiplier perturbations regressed
//          (R5/R7/R8/R11/R13/R14/R15/R19/R20). Gemm is at this family's floor.

#define M_DIM 4096
#define N_DIM 4096
#define K_DIM 8192
#define K_LOCAL 1024
#define RANKS 8
#define NT 128  // K-tiles: RANKS * (K_LOCAL/64)

typedef __bf16 bf16x8 __attribute__((ext_vector_type(8)));
typedef float f32x4 __attribute__((ext_vector_type(4)));

__device__ __forceinline__ unsigned short f2bf(float f) {
    unsigned int u = __float_as_uint(f);
    unsigned int r = (u + 0x7fffu + ((u >> 16) & 1u)) >> 16;
    return (unsigned short)r;
}

// ---------- Phase 1: linear fp32 -> bf16 cast (R22) ----------
// Block owns a contiguous 8192-elem (32KB fp32) region. Iter i, thread t
// covers elems i*1024 + t*4 (each wave-instruction 1KB lane-contiguous).
// All 8 nt-loads issued before any convert/store (8x16B in flight/thread).
__global__ __launch_bounds__(256) void convert_cast(
    const float* __restrict__ srcA, unsigned short* __restrict__ dstA,
    const float* __restrict__ srcB, unsigned short* __restrict__ dstB,
    int blocks_per_tensor) {
    const float* src = srcA;
    unsigned short* dst = dstA;
    int b = blockIdx.x;
    if (b >= blocks_per_tensor) { b -= blocks_per_tensor; src = srcB; dst = dstB; }
    const size_t base = (size_t)b * 8192 + threadIdx.x * 4;
    f32x4 v[8];
#pragma unroll
    for (int i = 0; i < 8; ++i)
        v[i] = __builtin_nontemporal_load((const f32x4*)(src + base + i * 1024));
#pragma unroll
    for (int i = 0; i < 8; ++i) {
        ushort4 o;
        o.x = f2bf(v[i].x); o.y = f2bf(v[i].y);
        o.z = f2bf(v[i].z); o.w = f2bf(v[i].w);
        *(ushort4*)(dst + base + i * 1024) = o;
    }
}

// ---------- Phase 2: 256^2 deep-prefetch 8-phase bf16 MFMA GEMM (R16) ----------
__device__ __forceinline__ void async_copy16(const unsigned short* g, unsigned short* l) {
    __builtin_amdgcn_global_load_lds(
        (const __attribute__((address_space(1))) void*)g,
        (__attribute__((address_space(3))) void*)l,
        16, 0, 0);
}

#define VM6()   asm volatile("s_waitcnt vmcnt(6)" ::: "memory")
#define VM0()   asm volatile("s_waitcnt vmcnt(0)" ::: "memory")
#define BAR()   __builtin_amdgcn_s_barrier()
#define SCHED0() __builtin_amdgcn_sched_barrier(0)

__global__ __launch_bounds__(512, 2) void gemm_bf16(
    const unsigned short* __restrict__ A,  // [R, M, K_LOCAL] bf16
    const unsigned short* __restrict__ B,  // [R, N, K_LOCAL] bf16
    float* __restrict__ C) {               // [M, N] fp32
    // Per-tensor-half regions: [buf][rowhalf][128 rows][64 k] (128B rows).
    // 16B chunk c of row r stored at chunk c ^ (r & 7) (0 conflicts, R3-R16).
    __shared__ __align__(16) unsigned short As[2][2][128][64];
    __shared__ __align__(16) unsigned short Bs[2][2][128][64];

    const int tid = threadIdx.x;   // 0..511
    const int lane = tid & 63;
    const int wave = tid >> 6;     // 0..7
    const int l15 = lane & 15;
    const int l4 = lane >> 4;      // 0..3
    const int wm2 = wave >> 2;     // 0..1 -> row block *128 (= A half read)
    const int wn4 = wave & 3;      // 0..3 -> col block *64

    // Bijective XCD swizzle: 256 blocks, each XCD owns a 4x8 tile sub-grid.
    const int bid = blockIdx.x;
    const int xcd = bid & 7;
    const int idx = bid >> 3;                       // 0..31
    const int trow = (xcd >> 1) * 4 + (idx >> 3);   // 0..15
    const int tcol = (xcd & 1) * 8 + (idx & 7);     // 0..15
    const int bm0 = trow * 256;
    const int bn0 = tcol * 256;

    // Stage unit = one tensor-half: 128 rows x 64 k x 2B = 16KB = 1024 chunks;
    // li = i*512 + tid: row = li>>3, cpos = li&7, global chunk g = cpos^(row&7).
    const unsigned short* gA[2];
    const unsigned short* gB[2];
    int lo[2];
#pragma unroll
    for (int i = 0; i < 2; ++i) {
        int li = i * 512 + tid;
        int row = li >> 3;
        int g = (li & 7) ^ (row & 7);
        gA[i] = A + (size_t)(bm0 + row) * K_LOCAL + g * 8;
        gB[i] = B + (size_t)(bn0 + row) * K_LOCAL + g * 8;
        lo[i] = li * 8;  // ushort units
    }

    auto stageA = [&](int t, int buf, int h) {
        const size_t off = (size_t)(t >> 4) * ((size_t)M_DIM * K_LOCAL)
                         + (size_t)((t & 15) << 6) + (size_t)h * (128 * K_LOCAL);
        unsigned short* l = &As[buf][h][0][0];
        async_copy16(gA[0] + off, l + lo[0]);
        async_copy16(gA[1] + off, l + lo[1]);
    };
    auto stageB = [&](int t, int buf, int h) {
        const size_t off = (size_t)(t >> 4) * ((size_t)M_DIM * K_LOCAL)
                         + (size_t)((t & 15) << 6) + (size_t)h * (128 * K_LOCAL);
        unsigned short* l = &Bs[buf][h][0][0];
        async_copy16(gB[0] + off, l + lo[0]);
        async_copy16(gB[1] + off, l + lo[1]);
    };

    // Fragment reads: k-chunk c = ks*4 + l4 stored at c ^ (row&7); frag rows
    // are <mult of 16> + l15, so row&7 == l15&7.
    const int swzk0 = ((l4 + 0) ^ (l15 & 7)) * 8;  // ks = 0
    const int swzk1 = ((l4 + 4) ^ (l15 & 7)) * 8;  // ks = 1
    const int hb = wn4 >> 1;                        // B half for this wave
    const int brow_base = (wn4 & 1) * 64 + l15;     // B row within half

    f32x4 acc[8][4] = {};
    bf16x8 aR[8], a1R[8], b0R[4], b1R[4];

    auto LDA = [&](bf16x8* dst, int buf, int mh) {
#pragma unroll
        for (int m = 0; m < 4; ++m) {
            const unsigned short* rp = &As[buf][wm2][mh * 64 + m * 16 + l15][0];
            dst[m * 2 + 0] = *(const bf16x8*)(rp + swzk0);
            dst[m * 2 + 1] = *(const bf16x8*)(rp + swzk1);
        }
    };
    auto LDB = [&](bf16x8* dst, int buf, int nh) {
#pragma unroll
        for (int n = 0; n < 2; ++n) {
            const unsigned short* rp = &Bs[buf][hb][brow_base + nh * 32 + n * 16][0];
            dst[n * 2 + 0] = *(const bf16x8*)(rp + swzk0);
            dst[n * 2 + 1] = *(const bf16x8*)(rp + swzk1);
        }
    };
    auto MFMA16 = [&](const bf16x8* a, const bf16x8* b, int mh, int nh) {
        __builtin_amdgcn_s_setprio(1);
#pragma unroll
        for (int m = 0; m < 4; ++m)
#pragma unroll
            for (int n = 0; n < 2; ++n)
#pragma unroll
                for (int ks = 0; ks < 2; ++ks)
                    acc[mh * 4 + m][nh * 2 + n] = __builtin_amdgcn_mfma_f32_16x16x32_bf16(
                        a[m * 2 + ks], b[n * 2 + ks], acc[mh * 4 + m][nh * 2 + n], 0, 0, 0);
        __builtin_amdgcn_s_setprio(0);
    };

    // Prologue: t0 all 4 units (8 loads), then B0/A0/B1 of t1 (6 loads).
    // VM6 retires exactly t0's 8; {B0,A0,B1}(t1) stay in flight.
    stageA(0, 0, 0); stageA(0, 0, 1); stageB(0, 0, 0); stageB(0, 0, 1);
    stageB(1, 1, 0); stageA(1, 1, 0); stageB(1, 1, 1);
    VM6(); BAR();

    // Per phase: {reads; stage; SCHED0; MFMA16; [VM6]; BAR}. SCHED0 pins the
    // issue order (stage-DMA early) at zero runtime cost; the single runtime
    // barrier per phase carries all cross-wave publication.
    for (int i = 0; i < NT / 2; ++i) {
        const int t1 = 2 * i + 1;
        const int t2 = (2 * i + 2) & (NT - 1);
        const int t3 = (2 * i + 3) & (NT - 1);
        // P0: Q00(t) | stage A1(t1)  [buf1.A1 read last at prev P6]
        LDA(aR, 0, 0); LDB(b0R, 0, 0); stageA(t1, 1, 1);
        SCHED0(); MFMA16(aR, b0R, 0, 0); BAR();
        // P1: Q01(t) | stage B0(t2)  [buf0.B0 read at P0]
        LDB(b1R, 0, 1); stageB(t2, 0, 0);
        SCHED0(); MFMA16(aR, b1R, 0, 1); BAR();
        // P2: Q10(t) | stage A0(t2)  [buf0.A0 read at P0]
        LDA(a1R, 0, 1); stageA(t2, 0, 0);
        SCHED0(); MFMA16(a1R, b0R, 1, 0); BAR();
        // P3: Q11(t) | stage B1(t2)  [buf0.B1 read at P1] | vmcnt(6): t1 lands
        stageB(t2, 0, 1);
        SCHED0(); MFMA16(a1R, b1R, 1, 1); VM6(); BAR();
        // P4: Q00(t1) | stage A1(t2) [buf0.A1 read at P2]
        LDA(aR, 1, 0); LDB(b0R, 1, 0); stageA(t2, 0, 1);
        SCHED0(); MFMA16(aR, b0R, 0, 0); BAR();
        // P5: Q01(t1) | stage B0(t3) [buf1.B0 read at P4]
        LDB(b1R, 1, 1); stageB(t3, 1, 0);
        SCHED0(); MFMA16(aR, b1R, 0, 1); BAR();
        // P6: Q10(t1) | stage A0(t3) [buf1.A0 read at P4]
        LDA(a1R, 1, 1); stageA(t3, 1, 0);
        SCHED0(); MFMA16(a1R, b0R, 1, 0); BAR();
        // P7: Q11(t1) | stage B1(t3) [buf1.B1 read at P5] | vmcnt(6): t2 lands
        stageB(t3, 1, 1);
        SCHED0(); MFMA16(a1R, b1R, 1, 1); VM6(); BAR();
    }
    VM0();  // drain outstanding DMA before exit

    // Epilogue: C/D layout col = lane&15, row = (lane>>4)*4 + reg.
#pragma unroll
    for (int m = 0; m < 8; ++m) {
        int row0 = bm0 + wm2 * 128 + m * 16 + l4 * 4;
#pragma unroll
        for (int n = 0; n < 4; ++n) {
            int col = bn0 + wn4 * 64 + n * 16 + l15;
#pragma unroll
            for (int rr = 0; rr < 4; ++rr)
                C[(size_t)(row0 + rr) * N_DIM + col] = acc[m][n][rr];
        }
    }
}

// ---------- Fallback (ws too small): naive fp32 tiled GEMM ----------
__global__ void gemm_naive(const float* __restrict__ A, const float* __restrict__ B,
                           float* __restrict__ C) {
    __shared__ float As[16][17];
    __shared__ float Bs[16][17];
    int tx = threadIdx.x, ty = threadIdx.y;
    int m = blockIdx.y * 16 + ty;
    int n0 = blockIdx.x * 16;
    float accv = 0.f;
    for (int kt = 0; kt < K_DIM; kt += 16) {
        int r = kt >> 10;
        int k = (kt & 1023) + tx;
        As[ty][tx] = A[((size_t)r * M_DIM + m) * K_LOCAL + k];
        Bs[ty][tx] = B[((size_t)r * N_DIM + (n0 + ty)) * K_LOCAL + k];
        __syncthreads();
#pragma unroll
        for (int kk = 0; kk < 16; ++kk) accv += As[ty][kk] * Bs[tx][kk];
        __syncthreads();
    }
    C[(size_t)m * N_DIM + n0 + tx] = accv;
}

extern "C" void kernel_launch(void* const* d_in, const int* in_sizes, int n_in,
                              void* d_out, int out_size, void* d_ws, size_t ws_size,
                              hipStream_t stream) {
    const float* inp = (const float*)d_in[0];
    const float* wgt = (const float*)d_in[1];
    float* out = (float*)d_out;

    const size_t elems = (size_t)M_DIM * K_DIM;              // 33,554,432 per tensor
    const size_t need = 2 * elems * sizeof(unsigned short);  // 128 MiB

    if (ws_size >= need) {
        unsigned short* Abf = (unsigned short*)d_ws;
        unsigned short* Bbf = Abf + elems;
        const int bpt = (int)(elems / 8192);      // 4096 blocks per tensor
        convert_cast<<<bpt * 2, 256, 0, stream>>>(inp, Abf, wgt, Bbf, bpt);
        gemm_bf16<<<256, 512, 0, stream>>>(Abf, Bbf, out);
    } else {
        dim3 grid(N_DIM / 16, M_DIM / 16);
        dim3 block(16, 16);
        gemm_naive<<<grid, block, 0, stream>>>(inp, wgt, out);
    }
}